// Round 10
// baseline (123.006 us; speedup 1.0000x reference)
//
#include <hip/hip_runtime.h>

// B=16, M=8, S=100, P=40, A=3, D=128, H=8, HD=16. Inputs fp32, output fp32.
// Algebra: feats = [a0,a1,a2,1] @ W4 (rank-4) =>
//   scores = pts4 @ W4qk (4x8); apool[seg,h,j] = softmax-pool of pts4 (K=32);
//   emb_pre = apool @ T + out_b  (T = 32x128, precomputed; MFMA K=32)
// R10: A2 LDS fixed 48->24KB => 4 blocks/CU (135->127us).
// R11/R12: intra-kernel flag handshake ABANDONED (spin storm / idle-dominated).
// R13: 200x1024 fat blocks REGRESSED (52us): latency-bound; cross-block
//   overlap at high blocks/CU is the thing that hides latency.
// R14: fence+atomic epilogue in hot kernel REGRESSED k_all 30->72us. Never.
// R15: epilogue stripped + A1/A2 chunk-XOR swizzle -> 126.6us.
// R16: k2 launch folded into k_pre (bmflag precompute from roads) -> 124.1us.
// R17/R18: single-plane bf16 weights -> 120.9us; absmax UNCHANGED (0.015625)
//   => checker error budget not dominated by GEMM precision; headroom exists.
// R19 (this round): single-plane bf16 HIDDEN activations (A2 hi only).
//   GEMM2 MFMA 48->24/wave, A2 traffic halved; LDS 34.6->22.6KB => 7
//   blocks/CU (was 4) for cross-block latency overlap. Hidden bf16 rounding
//   adds ~1.2e-3 std to y (vs accepted 0.0156 absmax). FAIL -> revert R9.
namespace {
constexpr int Sn = 100;
constexpr int Nn = 12800;               // B*M*S
constexpr int OUT0 = 1638400;           // S*B*M*D
}

using bf16x8 = __attribute__((ext_vector_type(8))) short;
using f32x4  = __attribute__((ext_vector_type(4))) float;
#define MFMA16(a, b, c) __builtin_amdgcn_mfma_f32_16x16x32_bf16((a), (b), (c), 0, 0, 0)

__device__ __forceinline__ unsigned short f2bf(float x) {
  unsigned int u = __float_as_uint(x);
  return (unsigned short)((u + 0x7FFFu + ((u >> 16) & 1u)) >> 16);
}
__device__ __forceinline__ float bf2f(unsigned short h) {
  return __uint_as_float(((unsigned int)h) << 16);
}
// chunk-level LDS swizzle: flips low-3 bits of the 16B-chunk index with its
// high bits. In-plane ushort index only (plane sizes are multiples of 512).
__device__ __forceinline__ int swz(int idx) {
  return idx ^ (((idx >> 6) & 7) << 3);
}

// ---------------------------------------------------------------------------
// K_PRE: 216 blocks x 256 thr.
//   blocks 0..7    : W4qk column h (t<128)
//   blocks 8..39   : T row hj -> Tf bf16 hi/lo fragments (t<128)
//   blocks 40..87  : w1/w2 repack into SINGLE-plane bf16 B-frag tiles
//   blocks 88..215 : per-bm all-empty scan of roads -> bmflag[128]
// ---------------------------------------------------------------------------
__global__ __launch_bounds__(256) void k_pre(
    const float* __restrict__ ms, const float* __restrict__ wq,
    const float* __restrict__ wk, const float* __restrict__ bq,
    const float* __restrict__ bk, const float* __restrict__ lin_w,
    const float* __restrict__ lin_b, const float* __restrict__ wv,
    const float* __restrict__ bv, const float* __restrict__ out_w,
    const float* __restrict__ w1g, const float* __restrict__ w2g,
    const float* __restrict__ roads,
    float* __restrict__ W4qk, unsigned short* __restrict__ w1f,
    unsigned short* __restrict__ w2f, unsigned short* __restrict__ Tf,
    unsigned* __restrict__ bmflag) {
  const int t = threadIdx.x;
  const int bid = blockIdx.x;
  __shared__ union {
    struct { float q[128]; float qkh[128]; float part[128]; float qbkh; } pq;
    struct { float part[128]; float w4wv[16]; } pt;
    unsigned anyv[4];
  } u;

  if (bid < 8) {
    const int h = bid;
    if (t < 128) {
      float s = bq[t];
      for (int c = 0; c < 128; ++c) s += ms[c] * wq[c * 128 + t];
      u.pq.q[t] = s;
    }
    __syncthreads();
    if (t < 128) {
      float a = 0.f;
#pragma unroll
      for (int j = 0; j < 16; ++j) a += u.pq.q[h * 16 + j] * wk[t * 128 + h * 16 + j];
      u.pq.qkh[t] = a * 0.25f;
      if (t == 0) {
        float b = 0.f;
#pragma unroll
        for (int j = 0; j < 16; ++j) b += u.pq.q[h * 16 + j] * bk[h * 16 + j];
        u.pq.qbkh = b * 0.25f;
      }
    }
    __syncthreads();
    if (t < 128) {
      const int j = t >> 5, cp = t & 31;
      float p = 0.f;
      for (int c = cp * 4; c < cp * 4 + 4; ++c) {
        const float w4 = (j < 3) ? lin_w[j * 128 + c] : lin_b[c];
        p += w4 * u.pq.qkh[c];
      }
      u.pq.part[t] = p;
    }
    __syncthreads();
    if (t < 4) {
      float sum = 0.f;
      for (int i = 0; i < 32; ++i) sum += u.pq.part[t * 32 + i];
      if (t == 3) sum += u.pq.qbkh;
      W4qk[t * 8 + h] = sum;
    }
  } else if (bid < 40) {
    const int hj = bid - 8;            // 0..31 (= k row of T)
    const int h = hj >> 2, j = hj & 3;
    if (t < 128) {
      const int cp = t & 7;
      float p = 0.f;
      for (int c = cp * 16; c < cp * 16 + 16; ++c) {
        const float w4 = (j < 3) ? lin_w[j * 128 + c] : lin_b[c];
        p += w4 * wv[c * 128 + (h * 16 + (t >> 3))];
      }
      u.pt.part[t] = p;
    }
    __syncthreads();
    if (t < 16) {
      float sum = 0.f;
      for (int i = 0; i < 8; ++i) sum += u.pt.part[t * 8 + i];
      if (j == 3) sum += bv[h * 16 + t];
      u.pt.w4wv[t] = sum;
    }
    __syncthreads();
    if (t < 128) {
      float acc = 0.f;
#pragma unroll
      for (int e2 = 0; e2 < 16; ++e2) acc += u.pt.w4wv[e2] * out_w[(h * 16 + e2) * 128 + t];
      // Tf slot: tile nt=t>>4, lane=(k/8)*16 + n%16 with k=hj, n=t.
      const int ntT = t >> 4, n16T = t & 15;
      const int quadT = hj >> 3;
      const int slot = ntT * 1024 + (quadT * 16 + n16T) * 8 + (hj & 7);
      const unsigned short hh = f2bf(acc);
      Tf[slot] = hh;
      Tf[slot + 512] = f2bf(acc - bf2f(hh));
    }
  } else if (bid < 88) {
    // repack w1 (128x384), w2 (384x128) SINGLE bf16 plane: 192 tiles x 512 us
    const int gid = (bid - 40) * 256 + t;
    const int tile = gid >> 6, lane = gid & 63;
    const int quad = lane >> 4, n16 = lane & 15;
    unsigned short hi[8];
    unsigned short* dst;
    if (tile < 96) {                 // w1: nt 0..23, kk 0..3
      const int nt = tile >> 2, kk = tile & 3;
      const int n = nt * 16 + n16;
#pragma unroll
      for (int j = 0; j < 8; ++j) {
        const int k = kk * 32 + quad * 8 + j;
        hi[j] = f2bf(w1g[k * 384 + n]);
      }
      dst = w1f + (size_t)tile * 512 + lane * 8;
    } else {                         // w2: nt2 0..7, kk2 0..11
      const int t2 = tile - 96;
      const int nt2 = t2 / 12, kk2 = t2 % 12;
      const int n = nt2 * 16 + n16;
#pragma unroll
      for (int j = 0; j < 8; ++j) {
        const int k = kk2 * 32 + quad * 8 + j;
        hi[j] = f2bf(w2g[k * 128 + n]);
      }
      dst = w2f + (size_t)(tile - 96) * 512 + lane * 8;
    }
#pragma unroll
    for (int j = 0; j < 8; ++j) dst[j] = hi[j];
  } else {
    // all-empty scan: one block per bm; 4000 float4 pts, test .w flags
    const int bm = bid - 88;
    const float4* r4 = (const float4*)roads + (size_t)bm * 4000;
    unsigned found = 0;
    for (int i = t; i < 4000; i += 256) found |= (r4[i].w != 0.f) ? 1u : 0u;
    const unsigned long long b = __ballot(found != 0);
    if ((t & 63) == 0) u.anyv[t >> 6] = (b != 0ULL) ? 1u : 0u;
    __syncthreads();
    if (t == 0)
      bmflag[bm] = (u.anyv[0] | u.anyv[1] | u.anyv[2] | u.anyv[3]) ? 0u : 1u;
  }
}

// ---------------------------------------------------------------------------
// K_ALL: 800 blocks x 256 thr, 16 segments each, 7 blocks/CU (22.6 KB LDS).
// pool (VALU) -> emb MFMA + LN1 -> GEMM1 -> GEMM2 -> LN2 -> out.
// Weights single-plane bf16; hidden (A2) single-plane bf16; emb (A1) hi/lo;
// Tf hi/lo. Residual in registers. A1/A2 chunk-swizzled. No device sync.
// ---------------------------------------------------------------------------
__global__ __launch_bounds__(256, 8) void k_all(
    const float* __restrict__ roads, const float* __restrict__ W4qk_g,
    const unsigned short* __restrict__ Tf, const float* __restrict__ out_b,
    const float* __restrict__ ln1_g, const float* __restrict__ ln1_b,
    const unsigned short* __restrict__ w1f, const unsigned short* __restrict__ w2f,
    const float* __restrict__ b1, const float* __restrict__ b2,
    const float* __restrict__ ln2_g, const float* __restrict__ ln2_b,
    const unsigned* __restrict__ bmflag, float* __restrict__ out) {
  const int t = threadIdx.x;
  const int n0 = blockIdx.x * 16;

  __shared__ union {
    float4 pts[640];                         // 10 KB (dead after pool)
    __align__(16) unsigned short A2[6144];   // hidden 16x384 hi only, 12 KB
  } u;
  __shared__ __align__(16) unsigned short A1[4096];   // emb 16x128 hi/lo, 8 KB
  __shared__ __align__(16) unsigned short ApF[1024];  // apool 16x32 hi/lo, 2 KB
  __shared__ float w4qk_l[32];
  __shared__ float lnr[16][4][2];

  // ---- stage pts + folded QK
  for (int i = t; i < 640; i += 256)
    u.pts[i] = ((const float4*)roads)[(size_t)n0 * 40 + i];
  if (t < 32) w4qk_l[t] = W4qk_g[t];
  __syncthreads();

  // ---- pool: 2 threads per (seg,h), 20 pts each; no max-sub (|scores|<~3)
  {
    const int sh = t >> 1, seg = sh >> 3, h = sh & 7;
    const int p0 = (t & 1) * 20;
    const float wa = w4qk_l[h], wb = w4qk_l[8 + h];
    const float wc = w4qk_l[16 + h], wd = w4qk_l[24 + h];
    float ax = 0.f, ay = 0.f, az = 0.f, den = 0.f;
    int nv = 0;
    for (int p = p0; p < p0 + 20; ++p) {
      const float4 pt = u.pts[seg * 40 + p];
      if (pt.w != 0.f) {
        const float e = __expf(wd + pt.x * wa + pt.y * wb + pt.z * wc);
        ax += e * pt.x; ay += e * pt.y; az += e * pt.z; den += e; ++nv;
      }
    }
    ax += __shfl_xor(ax, 1); ay += __shfl_xor(ay, 1); az += __shfl_xor(az, 1);
    den += __shfl_xor(den, 1); nv += __shfl_xor(nv, 1);
    if ((t & 1) == 0) {
      if (nv == 0) {  // empty seg: reference unmasks pt 0 -> attn=[1,0,...]
        const float4 z = u.pts[seg * 40];
        ax = z.x; ay = z.y; az = z.z; den = 1.f;
      }
      const float inv = 1.f / den;
      const float v[4] = {ax * inv, ay * inv, az * inv, 1.f};
      ushort4 hi, lo;
      unsigned short* hp = (unsigned short*)&hi;
      unsigned short* lp = (unsigned short*)&lo;
#pragma unroll
      for (int c = 0; c < 4; ++c) { hp[c] = f2bf(v[c]); lp[c] = f2bf(v[c] - bf2f(hp[c])); }
      // A-frag slot: m=seg, k=h*4+c -> quad=h>>1, j=(h&1)*4+c
      const int slot = ((h >> 1) * 16 + seg) * 8 + (h & 1) * 4;
      *(ushort4*)&ApF[slot] = hi;
      *(ushort4*)&ApF[512 + slot] = lo;
      if (h == 0) {
        const int nn = n0 + seg;
        float mv = 0.f;
        if (nv == 0) {
          mv = 1.f;
          // all-empty bm: reference unmasks seg 0 (seg_mask fix)
          if (nn % 100 == 0 && bmflag[nn / 100]) mv = 0.f;
        }
        out[OUT0 + nn] = mv;
      }
    }
  }
  __syncthreads();

  const int w = t >> 6, lane = t & 63;
  const int quad = lane >> 4, nlane = lane & 15;

  // ---- emb = apool @ T + out_b (MFMA, K=32); wave w owns cols w*32..+31
  float embv[2][4];  // [n2][r]
  {
    const bf16x8 ahi = *(const bf16x8*)&ApF[lane * 8];
    const bf16x8 alo = *(const bf16x8*)&ApF[512 + lane * 8];
#pragma unroll
    for (int n2 = 0; n2 < 2; ++n2) {
      const int nt = w * 2 + n2;
      const unsigned short* tp = Tf + (size_t)nt * 1024;
      const bf16x8 bhi = *(const bf16x8*)(tp + lane * 8);
      const bf16x8 blo = *(const bf16x8*)(tp + 512 + lane * 8);
      f32x4 acc = (f32x4){0.f, 0.f, 0.f, 0.f};
      acc = MFMA16(alo, bhi, acc);
      acc = MFMA16(ahi, blo, acc);
      acc = MFMA16(ahi, bhi, acc);
      const float ob = out_b[nt * 16 + nlane];
#pragma unroll
      for (int r = 0; r < 4; ++r) embv[n2][r] = acc[r] + ob;
    }
    // LN1 partials: per row, sum over this wave's 2 cols then 16 nlanes
#pragma unroll
    for (int r = 0; r < 4; ++r) {
      float s = embv[0][r] + embv[1][r];
      float v = embv[0][r] * embv[0][r] + embv[1][r] * embv[1][r];
#pragma unroll
      for (int m = 1; m < 16; m <<= 1) { s += __shfl_xor(s, m); v += __shfl_xor(v, m); }
      if (nlane == 0) { lnr[quad * 4 + r][w][0] = s; lnr[quad * 4 + r][w][1] = v; }
    }
  }
  __syncthreads();

  // ---- LN1 apply + write emb to A1 (A-frag hi/lo, swizzled); residual in regs
  float eres[2][4];
#pragma unroll
  for (int r = 0; r < 4; ++r) {
    const int row = quad * 4 + r;
    const float mu = (lnr[row][0][0] + lnr[row][1][0] + lnr[row][2][0] + lnr[row][3][0]) * (1.f / 128.f);
    const float msq = (lnr[row][0][1] + lnr[row][1][1] + lnr[row][2][1] + lnr[row][3][1]) * (1.f / 128.f);
    const float rstd = rsqrtf(msq - mu * mu + 1e-5f);
#pragma unroll
    for (int n2 = 0; n2 < 2; ++n2) {
      const int col = (w * 2 + n2) * 16 + nlane;
      const float e = (embv[n2][r] - mu) * rstd * ln1_g[col] + ln1_b[col];
      eres[n2][r] = e;
      const unsigned short hh = f2bf(e), hl = f2bf(e - bf2f(hh));
      const int kk = col >> 5, q2 = (col >> 3) & 3, j = col & 7;
      const int idx = swz(kk * 512 + (q2 * 16 + row) * 8 + j);
      A1[idx] = hh; A1[2048 + idx] = hl;
    }
  }
  __syncthreads();

  // ---- GEMM1: hidden = relu(emb @ w1 + b1); wave w owns nt w*6..w*6+5
#pragma unroll
  for (int nti = 0; nti < 6; ++nti) {
    const int nt = w * 6 + nti;
    f32x4 acc = (f32x4){0.f, 0.f, 0.f, 0.f};
#pragma unroll
    for (int kk = 0; kk < 4; ++kk) {
      const int ra = swz(kk * 512 + lane * 8);
      const bf16x8 ahi = *(const bf16x8*)&A1[ra];
      const bf16x8 alo = *(const bf16x8*)&A1[2048 + ra];
      const bf16x8 bhi = *(const bf16x8*)(w1f + (size_t)(nt * 4 + kk) * 512 + lane * 8);
      acc = MFMA16(alo, bhi, acc);
      acc = MFMA16(ahi, bhi, acc);
    }
    const int col = nt * 16 + nlane;
    const float bias = b1[col];
    const int kk2 = col >> 5, qA = (col >> 3) & 3, jA = col & 7;
#pragma unroll
    for (int r = 0; r < 4; ++r) {
      const float h = fmaxf(acc[r] + bias, 0.f);
      const int idx = swz(kk2 * 512 + (qA * 16 + quad * 4 + r) * 8 + jA);
      u.A2[idx] = f2bf(h);
    }
  }
  __syncthreads();

  // ---- GEMM2: y = hidden @ w2; wave w owns cols w*32..+31 (nt2 = w*2+n2)
  f32x4 acc2[2];
  acc2[0] = (f32x4){0.f, 0.f, 0.f, 0.f};
  acc2[1] = (f32x4){0.f, 0.f, 0.f, 0.f};
#pragma unroll 4
  for (int kk2 = 0; kk2 < 12; ++kk2) {
    const int ra = swz(kk2 * 512 + lane * 8);
    const bf16x8 ahi = *(const bf16x8*)&u.A2[ra];
#pragma unroll
    for (int n2 = 0; n2 < 2; ++n2) {
      const bf16x8 bhi = *(const bf16x8*)(w2f + (size_t)((w * 2 + n2) * 12 + kk2) * 512 + lane * 8);
      acc2[n2] = MFMA16(ahi, bhi, acc2[n2]);
    }
  }

  // ---- epilogue: bias + register residual + LN2 + store
  float y[2][4];
#pragma unroll
  for (int n2 = 0; n2 < 2; ++n2) {
    const int col = (w * 2 + n2) * 16 + nlane;
    const float bb = b2[col];
#pragma unroll
    for (int r = 0; r < 4; ++r) y[n2][r] = acc2[n2][r] + bb + eres[n2][r];
  }
#pragma unroll
  for (int r = 0; r < 4; ++r) {
    float s = y[0][r] + y[1][r];
    float v = y[0][r] * y[0][r] + y[1][r] * y[1][r];
#pragma unroll
    for (int m = 1; m < 16; m <<= 1) { s += __shfl_xor(s, m); v += __shfl_xor(v, m); }
    if (nlane == 0) { lnr[quad * 4 + r][w][0] = s; lnr[quad * 4 + r][w][1] = v; }
  }
  __syncthreads();
#pragma unroll
  for (int r = 0; r < 4; ++r) {
    const int row = quad * 4 + r;
    const float mu = (lnr[row][0][0] + lnr[row][1][0] + lnr[row][2][0] + lnr[row][3][0]) * (1.f / 128.f);
    const float msq = (lnr[row][0][1] + lnr[row][1][1] + lnr[row][2][1] + lnr[row][3][1]) * (1.f / 128.f);
    const float rstd = rsqrtf(msq - mu * mu + 1e-5f);
    const int n = n0 + row, si = n % 100, bm = n / 100;
#pragma unroll
    for (int n2 = 0; n2 < 2; ++n2) {
      const int col = (w * 2 + n2) * 16 + nlane;
      out[(size_t)si * 16384 + bm * 128 + col] =
          (y[n2][r] - mu) * rstd * ln2_g[col] + ln2_b[col];
    }
  }
}

extern "C" void kernel_launch(void* const* d_in, const int* in_sizes, int n_in,
                              void* d_out, int out_size, void* d_ws, size_t ws_size,
                              hipStream_t stream) {
  const float* roads = (const float*)d_in[0];
  const float* ms    = (const float*)d_in[2];
  const float* lin_w = (const float*)d_in[3];
  const float* lin_b = (const float*)d_in[4];
  const float* wq    = (const float*)d_in[5];
  const float* wk    = (const float*)d_in[6];
  const float* wv    = (const float*)d_in[7];
  const float* bq    = (const float*)d_in[8];
  const float* bk    = (const float*)d_in[9];
  const float* bv    = (const float*)d_in[10];
  const float* out_w = (const float*)d_in[11];
  const float* out_b = (const float*)d_in[12];
  const float* ln1_g = (const float*)d_in[13];
  const float* ln1_b = (const float*)d_in[14];
  const float* w1    = (const float*)d_in[15];
  const float* b1    = (const float*)d_in[16];
  const float* w2    = (const float*)d_in[17];
  const float* b2    = (const float*)d_in[18];
  const float* ln2_g = (const float*)d_in[19];
  const float* ln2_b = (const float*)d_in[20];

  float* out = (float*)d_out;
  float* W4qk = (float*)d_ws;                            // 32 f
  unsigned short* w1f = (unsigned short*)(W4qk + 32);    // 96 KiB (single plane)
  unsigned short* w2f = w1f + 96 * 512;                  // 96 KiB (single plane)
  unsigned short* Tf  = w2f + 96 * 512;                  // 16 KiB (hi/lo)
  unsigned* bmflag = (unsigned*)(Tf + 8 * 1024);         // 128 u32

  k_pre<<<216, 256, 0, stream>>>(ms, wq, wk, bq, bk, lin_w, lin_b, wv, bv, out_w,
                                 w1, w2, roads, W4qk, w1f, w2f, Tf, bmflag);
  k_all<<<Nn / 16, 256, 0, stream>>>(roads, W4qk, Tf, out_b, ln1_g, ln1_b,
                                     w1f, w2f, b1, b2, ln2_g, ln2_b, bmflag, out);
}

// Round 11
// 120.853 us; speedup vs baseline: 1.0178x; 1.0178x over previous
//
#include <hip/hip_runtime.h>

// B=16, M=8, S=100, P=40, A=3, D=128, H=8, HD=16. Inputs fp32, output fp32.
// Algebra: feats = [a0,a1,a2,1] @ W4 (rank-4) =>
//   scores = pts4 @ W4qk (4x8); apool[seg,h,j] = softmax-pool of pts4 (K=32);
//   emb_pre = apool @ T + out_b  (T = 32x128, precomputed; MFMA K=32)
// R10: A2 LDS fixed 48->24KB => 4 blocks/CU (135->127us).
// R11/R12: intra-kernel flag handshake ABANDONED (spin storm / idle-dominated).
// R13: 200x1024 fat blocks REGRESSED (52us): latency-bound; 4 blocks/CU
//   cross-block overlap is what hides latency.
// R14: fence+atomic epilogue in hot kernel REGRESSED k_all 30->72us. Never.
// R15: epilogue stripped + A1/A2 chunk-XOR swizzle -> 126.6us.
// R16: k2 launch folded into k_pre (bmflag precompute from roads) -> 124.1us.
// R17/R18: single-plane bf16 weights -> 120.9us (BEST); absmax unchanged.
// R19: A2 single-plane + 7 blocks/CU REGRESSED (+2.1us): at 4 blocks/CU
//   latency already hidden; more blocks = more L2 weight-stream contention;
//   GEMM2 wasn't critical path. Precision lever exhausted.
// R20 (this round): REVERT to R18 verbatim (best measured 120.9us). Budget:
//   ~85-90us harness-fixed (2x256MiB poison fills at HBM roofline + gaps),
//   k_pre ~5us, k_all ~25us latency-bound with all structural levers tested.
namespace {
constexpr int Sn = 100;
constexpr int Nn = 12800;               // B*M*S
constexpr int OUT0 = 1638400;           // S*B*M*D
}

using bf16x8 = __attribute__((ext_vector_type(8))) short;
using f32x4  = __attribute__((ext_vector_type(4))) float;
#define MFMA16(a, b, c) __builtin_amdgcn_mfma_f32_16x16x32_bf16((a), (b), (c), 0, 0, 0)

__device__ __forceinline__ unsigned short f2bf(float x) {
  unsigned int u = __float_as_uint(x);
  return (unsigned short)((u + 0x7FFFu + ((u >> 16) & 1u)) >> 16);
}
__device__ __forceinline__ float bf2f(unsigned short h) {
  return __uint_as_float(((unsigned int)h) << 16);
}
// chunk-level LDS swizzle: flips low-3 bits of the 16B-chunk index with its
// high bits. In-plane ushort index only (plane sizes are multiples of 512).
__device__ __forceinline__ int swz(int idx) {
  return idx ^ (((idx >> 6) & 7) << 3);
}

// ---------------------------------------------------------------------------
// K_PRE: 216 blocks x 256 thr.
//   blocks 0..7    : W4qk column h (t<128)
//   blocks 8..39   : T row hj -> Tf bf16 hi/lo fragments (t<128)
//   blocks 40..87  : w1/w2 repack into SINGLE-plane bf16 B-frag tiles
//   blocks 88..215 : per-bm all-empty scan of roads -> bmflag[128]
// ---------------------------------------------------------------------------
__global__ __launch_bounds__(256) void k_pre(
    const float* __restrict__ ms, const float* __restrict__ wq,
    const float* __restrict__ wk, const float* __restrict__ bq,
    const float* __restrict__ bk, const float* __restrict__ lin_w,
    const float* __restrict__ lin_b, const float* __restrict__ wv,
    const float* __restrict__ bv, const float* __restrict__ out_w,
    const float* __restrict__ w1g, const float* __restrict__ w2g,
    const float* __restrict__ roads,
    float* __restrict__ W4qk, unsigned short* __restrict__ w1f,
    unsigned short* __restrict__ w2f, unsigned short* __restrict__ Tf,
    unsigned* __restrict__ bmflag) {
  const int t = threadIdx.x;
  const int bid = blockIdx.x;
  __shared__ union {
    struct { float q[128]; float qkh[128]; float part[128]; float qbkh; } pq;
    struct { float part[128]; float w4wv[16]; } pt;
    unsigned anyv[4];
  } u;

  if (bid < 8) {
    const int h = bid;
    if (t < 128) {
      float s = bq[t];
      for (int c = 0; c < 128; ++c) s += ms[c] * wq[c * 128 + t];
      u.pq.q[t] = s;
    }
    __syncthreads();
    if (t < 128) {
      float a = 0.f;
#pragma unroll
      for (int j = 0; j < 16; ++j) a += u.pq.q[h * 16 + j] * wk[t * 128 + h * 16 + j];
      u.pq.qkh[t] = a * 0.25f;
      if (t == 0) {
        float b = 0.f;
#pragma unroll
        for (int j = 0; j < 16; ++j) b += u.pq.q[h * 16 + j] * bk[h * 16 + j];
        u.pq.qbkh = b * 0.25f;
      }
    }
    __syncthreads();
    if (t < 128) {
      const int j = t >> 5, cp = t & 31;
      float p = 0.f;
      for (int c = cp * 4; c < cp * 4 + 4; ++c) {
        const float w4 = (j < 3) ? lin_w[j * 128 + c] : lin_b[c];
        p += w4 * u.pq.qkh[c];
      }
      u.pq.part[t] = p;
    }
    __syncthreads();
    if (t < 4) {
      float sum = 0.f;
      for (int i = 0; i < 32; ++i) sum += u.pq.part[t * 32 + i];
      if (t == 3) sum += u.pq.qbkh;
      W4qk[t * 8 + h] = sum;
    }
  } else if (bid < 40) {
    const int hj = bid - 8;            // 0..31 (= k row of T)
    const int h = hj >> 2, j = hj & 3;
    if (t < 128) {
      const int cp = t & 7;
      float p = 0.f;
      for (int c = cp * 16; c < cp * 16 + 16; ++c) {
        const float w4 = (j < 3) ? lin_w[j * 128 + c] : lin_b[c];
        p += w4 * wv[c * 128 + (h * 16 + (t >> 3))];
      }
      u.pt.part[t] = p;
    }
    __syncthreads();
    if (t < 16) {
      float sum = 0.f;
      for (int i = 0; i < 8; ++i) sum += u.pt.part[t * 8 + i];
      if (j == 3) sum += bv[h * 16 + t];
      u.pt.w4wv[t] = sum;
    }
    __syncthreads();
    if (t < 128) {
      float acc = 0.f;
#pragma unroll
      for (int e2 = 0; e2 < 16; ++e2) acc += u.pt.w4wv[e2] * out_w[(h * 16 + e2) * 128 + t];
      // Tf slot: tile nt=t>>4, lane=(k/8)*16 + n%16 with k=hj, n=t.
      const int ntT = t >> 4, n16T = t & 15;
      const int quadT = hj >> 3;
      const int slot = ntT * 1024 + (quadT * 16 + n16T) * 8 + (hj & 7);
      const unsigned short hh = f2bf(acc);
      Tf[slot] = hh;
      Tf[slot + 512] = f2bf(acc - bf2f(hh));
    }
  } else if (bid < 88) {
    // repack w1 (128x384), w2 (384x128) SINGLE bf16 plane: 192 tiles x 512 us
    const int gid = (bid - 40) * 256 + t;
    const int tile = gid >> 6, lane = gid & 63;
    const int quad = lane >> 4, n16 = lane & 15;
    unsigned short hi[8];
    unsigned short* dst;
    if (tile < 96) {                 // w1: nt 0..23, kk 0..3
      const int nt = tile >> 2, kk = tile & 3;
      const int n = nt * 16 + n16;
#pragma unroll
      for (int j = 0; j < 8; ++j) {
        const int k = kk * 32 + quad * 8 + j;
        hi[j] = f2bf(w1g[k * 384 + n]);
      }
      dst = w1f + (size_t)tile * 512 + lane * 8;
    } else {                         // w2: nt2 0..7, kk2 0..11
      const int t2 = tile - 96;
      const int nt2 = t2 / 12, kk2 = t2 % 12;
      const int n = nt2 * 16 + n16;
#pragma unroll
      for (int j = 0; j < 8; ++j) {
        const int k = kk2 * 32 + quad * 8 + j;
        hi[j] = f2bf(w2g[k * 128 + n]);
      }
      dst = w2f + (size_t)(tile - 96) * 512 + lane * 8;
    }
#pragma unroll
    for (int j = 0; j < 8; ++j) dst[j] = hi[j];
  } else {
    // all-empty scan: one block per bm; 4000 float4 pts, test .w flags
    const int bm = bid - 88;
    const float4* r4 = (const float4*)roads + (size_t)bm * 4000;
    unsigned found = 0;
    for (int i = t; i < 4000; i += 256) found |= (r4[i].w != 0.f) ? 1u : 0u;
    const unsigned long long b = __ballot(found != 0);
    if ((t & 63) == 0) u.anyv[t >> 6] = (b != 0ULL) ? 1u : 0u;
    __syncthreads();
    if (t == 0)
      bmflag[bm] = (u.anyv[0] | u.anyv[1] | u.anyv[2] | u.anyv[3]) ? 0u : 1u;
  }
}

// ---------------------------------------------------------------------------
// K_ALL: 800 blocks x 256 thr, 16 segments each, 4 blocks/CU (34.6 KB LDS).
// pool (VALU) -> emb MFMA + LN1 -> GEMM1 -> GEMM2 -> LN2 -> out.
// Weights single-plane bf16 (2 chained MFMAs); activations hi/lo; Tf hi/lo.
// Residual in registers. A1/A2 chunk-swizzled. No device-scope sync (R14).
// ---------------------------------------------------------------------------
__global__ __launch_bounds__(256, 4) void k_all(
    const float* __restrict__ roads, const float* __restrict__ W4qk_g,
    const unsigned short* __restrict__ Tf, const float* __restrict__ out_b,
    const float* __restrict__ ln1_g, const float* __restrict__ ln1_b,
    const unsigned short* __restrict__ w1f, const unsigned short* __restrict__ w2f,
    const float* __restrict__ b1, const float* __restrict__ b2,
    const float* __restrict__ ln2_g, const float* __restrict__ ln2_b,
    const unsigned* __restrict__ bmflag, float* __restrict__ out) {
  const int t = threadIdx.x;
  const int n0 = blockIdx.x * 16;

  __shared__ union {
    float4 pts[640];                         // 10 KB (dead after pool)
    __align__(16) unsigned short A2[12288];  // hidden 16x384 hi/lo, 24 KB
  } u;
  __shared__ __align__(16) unsigned short A1[4096];   // emb 16x128 hi/lo, 8 KB
  __shared__ __align__(16) unsigned short ApF[1024];  // apool 16x32 hi/lo, 2 KB
  __shared__ float w4qk_l[32];
  __shared__ float lnr[16][4][2];

  // ---- stage pts + folded QK
  for (int i = t; i < 640; i += 256)
    u.pts[i] = ((const float4*)roads)[(size_t)n0 * 40 + i];
  if (t < 32) w4qk_l[t] = W4qk_g[t];
  __syncthreads();

  // ---- pool: 2 threads per (seg,h), 20 pts each; no max-sub (|scores|<~3)
  {
    const int sh = t >> 1, seg = sh >> 3, h = sh & 7;
    const int p0 = (t & 1) * 20;
    const float wa = w4qk_l[h], wb = w4qk_l[8 + h];
    const float wc = w4qk_l[16 + h], wd = w4qk_l[24 + h];
    float ax = 0.f, ay = 0.f, az = 0.f, den = 0.f;
    int nv = 0;
    for (int p = p0; p < p0 + 20; ++p) {
      const float4 pt = u.pts[seg * 40 + p];
      if (pt.w != 0.f) {
        const float e = __expf(wd + pt.x * wa + pt.y * wb + pt.z * wc);
        ax += e * pt.x; ay += e * pt.y; az += e * pt.z; den += e; ++nv;
      }
    }
    ax += __shfl_xor(ax, 1); ay += __shfl_xor(ay, 1); az += __shfl_xor(az, 1);
    den += __shfl_xor(den, 1); nv += __shfl_xor(nv, 1);
    if ((t & 1) == 0) {
      if (nv == 0) {  // empty seg: reference unmasks pt 0 -> attn=[1,0,...]
        const float4 z = u.pts[seg * 40];
        ax = z.x; ay = z.y; az = z.z; den = 1.f;
      }
      const float inv = 1.f / den;
      const float v[4] = {ax * inv, ay * inv, az * inv, 1.f};
      ushort4 hi, lo;
      unsigned short* hp = (unsigned short*)&hi;
      unsigned short* lp = (unsigned short*)&lo;
#pragma unroll
      for (int c = 0; c < 4; ++c) { hp[c] = f2bf(v[c]); lp[c] = f2bf(v[c] - bf2f(hp[c])); }
      // A-frag slot: m=seg, k=h*4+c -> quad=h>>1, j=(h&1)*4+c
      const int slot = ((h >> 1) * 16 + seg) * 8 + (h & 1) * 4;
      *(ushort4*)&ApF[slot] = hi;
      *(ushort4*)&ApF[512 + slot] = lo;
      if (h == 0) {
        const int nn = n0 + seg;
        float mv = 0.f;
        if (nv == 0) {
          mv = 1.f;
          // all-empty bm: reference unmasks seg 0 (seg_mask fix)
          if (nn % 100 == 0 && bmflag[nn / 100]) mv = 0.f;
        }
        out[OUT0 + nn] = mv;
      }
    }
  }
  __syncthreads();

  const int w = t >> 6, lane = t & 63;
  const int quad = lane >> 4, nlane = lane & 15;

  // ---- emb = apool @ T + out_b (MFMA, K=32); wave w owns cols w*32..+31
  float embv[2][4];  // [n2][r]
  {
    const bf16x8 ahi = *(const bf16x8*)&ApF[lane * 8];
    const bf16x8 alo = *(const bf16x8*)&ApF[512 + lane * 8];
#pragma unroll
    for (int n2 = 0; n2 < 2; ++n2) {
      const int nt = w * 2 + n2;
      const unsigned short* tp = Tf + (size_t)nt * 1024;
      const bf16x8 bhi = *(const bf16x8*)(tp + lane * 8);
      const bf16x8 blo = *(const bf16x8*)(tp + 512 + lane * 8);
      f32x4 acc = (f32x4){0.f, 0.f, 0.f, 0.f};
      acc = MFMA16(alo, bhi, acc);
      acc = MFMA16(ahi, blo, acc);
      acc = MFMA16(ahi, bhi, acc);
      const float ob = out_b[nt * 16 + nlane];
#pragma unroll
      for (int r = 0; r < 4; ++r) embv[n2][r] = acc[r] + ob;
    }
    // LN1 partials: per row, sum over this wave's 2 cols then 16 nlanes
#pragma unroll
    for (int r = 0; r < 4; ++r) {
      float s = embv[0][r] + embv[1][r];
      float v = embv[0][r] * embv[0][r] + embv[1][r] * embv[1][r];
#pragma unroll
      for (int m = 1; m < 16; m <<= 1) { s += __shfl_xor(s, m); v += __shfl_xor(v, m); }
      if (nlane == 0) { lnr[quad * 4 + r][w][0] = s; lnr[quad * 4 + r][w][1] = v; }
    }
  }
  __syncthreads();

  // ---- LN1 apply + write emb to A1 (A-frag hi/lo, swizzled); residual in regs
  float eres[2][4];
#pragma unroll
  for (int r = 0; r < 4; ++r) {
    const int row = quad * 4 + r;
    const float mu = (lnr[row][0][0] + lnr[row][1][0] + lnr[row][2][0] + lnr[row][3][0]) * (1.f / 128.f);
    const float msq = (lnr[row][0][1] + lnr[row][1][1] + lnr[row][2][1] + lnr[row][3][1]) * (1.f / 128.f);
    const float rstd = rsqrtf(msq - mu * mu + 1e-5f);
#pragma unroll
    for (int n2 = 0; n2 < 2; ++n2) {
      const int col = (w * 2 + n2) * 16 + nlane;
      const float e = (embv[n2][r] - mu) * rstd * ln1_g[col] + ln1_b[col];
      eres[n2][r] = e;
      const unsigned short hh = f2bf(e), hl = f2bf(e - bf2f(hh));
      const int kk = col >> 5, q2 = (col >> 3) & 3, j = col & 7;
      const int idx = swz(kk * 512 + (q2 * 16 + row) * 8 + j);
      A1[idx] = hh; A1[2048 + idx] = hl;
    }
  }
  __syncthreads();

  // ---- GEMM1: hidden = relu(emb @ w1 + b1); wave w owns nt w*6..w*6+5
#pragma unroll
  for (int nti = 0; nti < 6; ++nti) {
    const int nt = w * 6 + nti;
    f32x4 acc = (f32x4){0.f, 0.f, 0.f, 0.f};
#pragma unroll
    for (int kk = 0; kk < 4; ++kk) {
      const int ra = swz(kk * 512 + lane * 8);
      const bf16x8 ahi = *(const bf16x8*)&A1[ra];
      const bf16x8 alo = *(const bf16x8*)&A1[2048 + ra];
      const bf16x8 bhi = *(const bf16x8*)(w1f + (size_t)(nt * 4 + kk) * 512 + lane * 8);
      acc = MFMA16(alo, bhi, acc);
      acc = MFMA16(ahi, bhi, acc);
    }
    const int col = nt * 16 + nlane;
    const float bias = b1[col];
    const int kk2 = col >> 5, qA = (col >> 3) & 3, jA = col & 7;
#pragma unroll
    for (int r = 0; r < 4; ++r) {
      const float h = fmaxf(acc[r] + bias, 0.f);
      const unsigned short hh = f2bf(h), hl = f2bf(h - bf2f(hh));
      const int idx = swz(kk2 * 512 + (qA * 16 + quad * 4 + r) * 8 + jA);
      u.A2[idx] = hh; u.A2[6144 + idx] = hl;
    }
  }
  __syncthreads();

  // ---- GEMM2: y = hidden @ w2; wave w owns cols w*32..+31 (nt2 = w*2+n2)
  f32x4 acc2[2];
  acc2[0] = (f32x4){0.f, 0.f, 0.f, 0.f};
  acc2[1] = (f32x4){0.f, 0.f, 0.f, 0.f};
#pragma unroll 4
  for (int kk2 = 0; kk2 < 12; ++kk2) {
    const int ra = swz(kk2 * 512 + lane * 8);
    const bf16x8 ahi = *(const bf16x8*)&u.A2[ra];
    const bf16x8 alo = *(const bf16x8*)&u.A2[6144 + ra];
#pragma unroll
    for (int n2 = 0; n2 < 2; ++n2) {
      const bf16x8 bhi = *(const bf16x8*)(w2f + (size_t)((w * 2 + n2) * 12 + kk2) * 512 + lane * 8);
      acc2[n2] = MFMA16(alo, bhi, acc2[n2]);
      acc2[n2] = MFMA16(ahi, bhi, acc2[n2]);
    }
  }

  // ---- epilogue: bias + register residual + LN2 + store
  float y[2][4];
#pragma unroll
  for (int n2 = 0; n2 < 2; ++n2) {
    const int col = (w * 2 + n2) * 16 + nlane;
    const float bb = b2[col];
#pragma unroll
    for (int r = 0; r < 4; ++r) y[n2][r] = acc2[n2][r] + bb + eres[n2][r];
  }
#pragma unroll
  for (int r = 0; r < 4; ++r) {
    float s = y[0][r] + y[1][r];
    float v = y[0][r] * y[0][r] + y[1][r] * y[1][r];
#pragma unroll
    for (int m = 1; m < 16; m <<= 1) { s += __shfl_xor(s, m); v += __shfl_xor(v, m); }
    if (nlane == 0) { lnr[quad * 4 + r][w][0] = s; lnr[quad * 4 + r][w][1] = v; }
  }
  __syncthreads();
#pragma unroll
  for (int r = 0; r < 4; ++r) {
    const int row = quad * 4 + r;
    const float mu = (lnr[row][0][0] + lnr[row][1][0] + lnr[row][2][0] + lnr[row][3][0]) * (1.f / 128.f);
    const float msq = (lnr[row][0][1] + lnr[row][1][1] + lnr[row][2][1] + lnr[row][3][1]) * (1.f / 128.f);
    const float rstd = rsqrtf(msq - mu * mu + 1e-5f);
    const int n = n0 + row, si = n % 100, bm = n / 100;
#pragma unroll
    for (int n2 = 0; n2 < 2; ++n2) {
      const int col = (w * 2 + n2) * 16 + nlane;
      out[(size_t)si * 16384 + bm * 128 + col] =
          (y[n2][r] - mu) * rstd * ln2_g[col] + ln2_b[col];
    }
  }
}

extern "C" void kernel_launch(void* const* d_in, const int* in_sizes, int n_in,
                              void* d_out, int out_size, void* d_ws, size_t ws_size,
                              hipStream_t stream) {
  const float* roads = (const float*)d_in[0];
  const float* ms    = (const float*)d_in[2];
  const float* lin_w = (const float*)d_in[3];
  const float* lin_b = (const float*)d_in[4];
  const float* wq    = (const float*)d_in[5];
  const float* wk    = (const float*)d_in[6];
  const float* wv    = (const float*)d_in[7];
  const float* bq    = (const float*)d_in[8];
  const float* bk    = (const float*)d_in[9];
  const float* bv    = (const float*)d_in[10];
  const float* out_w = (const float*)d_in[11];
  const float* out_b = (const float*)d_in[12];
  const float* ln1_g = (const float*)d_in[13];
  const float* ln1_b = (const float*)d_in[14];
  const float* w1    = (const float*)d_in[15];
  const float* b1    = (const float*)d_in[16];
  const float* w2    = (const float*)d_in[17];
  const float* b2    = (const float*)d_in[18];
  const float* ln2_g = (const float*)d_in[19];
  const float* ln2_b = (const float*)d_in[20];

  float* out = (float*)d_out;
  float* W4qk = (float*)d_ws;                            // 32 f
  unsigned short* w1f = (unsigned short*)(W4qk + 32);    // 96 KiB (single plane)
  unsigned short* w2f = w1f + 96 * 512;                  // 96 KiB (single plane)
  unsigned short* Tf  = w2f + 96 * 512;                  // 16 KiB (hi/lo)
  unsigned* bmflag = (unsigned*)(Tf + 8 * 1024);         // 128 u32

  k_pre<<<216, 256, 0, stream>>>(ms, wq, wk, bq, bk, lin_w, lin_b, wv, bv, out_w,
                                 w1, w2, roads, W4qk, w1f, w2f, Tf, bmflag);
  k_all<<<Nn / 16, 256, 0, stream>>>(roads, W4qk, Tf, out_b, ln1_g, ln1_b,
                                     w1f, w2f, b1, b2, ln2_g, ln2_b, bmflag, out);
}